// Round 6
// baseline (46.520 us; speedup 1.0000x reference)
//
#include <hip/hip_runtime.h>

#define F_ALPHA 0.25f
#define F_EPS   1e-8f
#define PN 50          // preds per block (uniform loop)
#define TTILE 256      // targets per block (one per thread)

// Kernel A: prescaled focal table. ftab[n*C+c] = 2*(pos-neg) + 2
__global__ void focal_table_kernel(const float* __restrict__ logits,
                                   float* __restrict__ ftab, int total) {
    int i = blockIdx.x * blockDim.x + threadIdx.x;
    if (i >= total) return;
    float x = logits[i];
    float p = 1.0f / (1.0f + expf(-x));
    float om = 1.0f - p;
    float pos = F_ALPHA * om * om * (-logf(p + F_EPS));
    float neg = (1.0f - F_ALPHA) * p * p * (-logf(om + F_EPS));
    ftab[i] = 2.0f * (pos - neg) + 2.0f;
}

// Kernel B: target-major. Thread owns one target (in registers); block loops
// over PN preds with a wave-uniform index -> pred box via s_load, row bases
// walk on SALU. Per pair: one 4B ftab gather + ~33 VALU + one coalesced store.
__global__ void __launch_bounds__(256)
cost_kernel(const float4* __restrict__ pred_boxes, // [N]
            const float4* __restrict__ tgt_boxes,  // [T]
            const int* __restrict__ tgt_ids,       // [T]
            const float* __restrict__ ftab,        // [N, C] prescaled
            float* __restrict__ out,               // [N, T]
            int N, int C, int T, int ntiles) {
    const int tid   = threadIdx.x;
    const int tile  = blockIdx.x % ntiles;          // uniform SALU magic-div
    const int chunk = blockIdx.x / ntiles;
    const int t  = tile * TTILE + tid;
    const int tc = min(t, T - 1);
    const bool tv = (t < T);

    // ---- target state: converted once, lives in registers ----
    float4 tb = tgt_boxes[tc];
    const int id = tgt_ids[tc];
    const float tx1 = tb.x - 0.5f * tb.z, ty1 = tb.y - 0.5f * tb.w;
    const float tx2 = tb.x + 0.5f * tb.z, ty2 = tb.y + 0.5f * tb.w;
    const float tarea = tb.z * tb.w;

    const int n0 = chunk * PN;
    const int n1 = min(n0 + PN, N);
    const float* __restrict__ frow = ftab + (size_t)n0 * C;  // uniform, walks
    float* __restrict__ orow = out + (size_t)n0 * T;         // uniform, walks

#pragma unroll 2
    for (int n = n0; n < n1; ++n) {
        float4 pb = pred_boxes[n];                 // uniform -> s_load_dwordx4
        float px1 = pb.x - 0.5f * pb.z, py1 = pb.y - 0.5f * pb.w;
        float px2 = pb.x + 0.5f * pb.z, py2 = pb.y + 0.5f * pb.w;
        float parea = pb.z * pb.w;

        float cls2 = frow[id];                     // 4B gather, L1/L2-warm row

        float l1 = (fabsf(pb.x - tb.x) + fabsf(pb.y - tb.y))
                 + (fabsf(pb.z - tb.z) + fabsf(pb.w - tb.w));

        float ix1 = fmaxf(px1, tx1), iy1 = fmaxf(py1, ty1);
        float ix2 = fminf(px2, tx2), iy2 = fminf(py2, ty2);
        float iw = fmaxf(ix2 - ix1, 0.0f), ih = fmaxf(iy2 - iy1, 0.0f);
        float inter = iw * ih;
        float uni = parea + tarea - inter;

        float ex1 = fminf(px1, tx1), ey1 = fminf(py1, ty1);
        float ex2 = fmaxf(px2, tx2), ey2 = fmaxf(py2, ty2);
        float earea = (ex2 - ex1) * (ey2 - ey1);   // wh >= 0 for [0,1) boxes

        float v = fmaf(5.0f, l1, cls2);            // 5*l1 + 2*cls + 2
        v = fmaf(-2.0f, inter * __builtin_amdgcn_rcpf(uni), v);
        v = fmaf(-2.0f, uni * __builtin_amdgcn_rcpf(earea), v);

        if (tv) orow[t] = v;                       // coalesced dword store
        frow += C; orow += T;
    }
}

extern "C" void kernel_launch(void* const* d_in, const int* in_sizes, int n_in,
                              void* d_out, int out_size, void* d_ws, size_t ws_size,
                              hipStream_t stream) {
    const float* logits = (const float*)d_in[0];   // [bs, Q, C]
    const float* pboxes = (const float*)d_in[1];   // [bs, Q, 4]
    const float* tboxes = (const float*)d_in[2];   // [T, 4]
    const int*   tids   = (const int*)d_in[3];     // [T]

    int N = in_sizes[1] / 4;          // bs*Q = 14400
    int C = in_sizes[0] / N;          // 91
    int T = in_sizes[2] / 4;          // 1600

    float* ftab = (float*)d_ws;       // N*C floats = 5.24 MB

    int totalA = N * C;
    focal_table_kernel<<<(totalA + 255) / 256, 256, 0, stream>>>(logits, ftab, totalA);

    int ntiles = (T + TTILE - 1) / TTILE;          // 7
    int chunks = (N + PN - 1) / PN;                // 288
    cost_kernel<<<ntiles * chunks, 256, 0, stream>>>(
        (const float4*)pboxes, (const float4*)tboxes, tids, ftab,
        (float*)d_out, N, C, T, ntiles);
}

// Round 7
// 32.952 us; speedup vs baseline: 1.4118x; 1.4118x over previous
//
#include <hip/hip_runtime.h>

#define F_ALPHA 0.25f
#define F_EPS   1e-8f
#define NB 4   // preds per block

// R5 structure (best so far) + transposed focal table:
// fclsT[c] = float4 of prescaled class cost (2*cls+2) for preds n0..n0+3.
// Inner loop does ONE ds_read_b128 per target instead of 4 conflicted b32 gathers.
__global__ void __launch_bounds__(256)
fused_cost_kernel(const float* __restrict__ logits,      // [N, C]
                  const float4* __restrict__ pred_boxes, // [N]
                  const float4* __restrict__ tgt_boxes,  // [T]
                  const int* __restrict__ tgt_ids,       // [T]
                  float* __restrict__ out,               // [N, T]
                  int N, int C, int T) {
    __shared__ float4 fclsT[96];                         // [class][NB preds]
    const int n0  = blockIdx.x * NB;
    const int tid = threadIdx.x;

    // ---- phase 1: wave w computes pred (n0+w)'s focal row, transposed ----
    {
        const int w = tid >> 6, l = tid & 63;
        const int n = min(n0 + w, N - 1);
        const float* lrow = logits + (size_t)n * C;
        for (int c = l; c < C; c += 64) {
            float x = lrow[c];
            float p = 1.0f / (1.0f + expf(-x));
            float om = 1.0f - p;
            float pos = F_ALPHA * om * om * (-logf(p + F_EPS));
            float neg = (1.0f - F_ALPHA) * p * p * (-logf(om + F_EPS));
            ((float*)fclsT)[c * NB + w] = 2.0f * (pos - neg) + 2.0f;
        }
    }

    // pred-side params (block-uniform) + output row pointers
    float pcx[NB], pcy[NB], pw_[NB], ph_[NB];
    float px1[NB], py1[NB], px2[NB], py2[NB], parea[NB];
    float* op[NB];
#pragma unroll
    for (int i = 0; i < NB; ++i) {
        const int n = min(n0 + i, N - 1);                // no-op when N % NB == 0
        float4 pb = pred_boxes[n];
        pcx[i] = pb.x; pcy[i] = pb.y; pw_[i] = pb.z; ph_[i] = pb.w;
        px1[i] = pb.x - 0.5f * pb.z;  py1[i] = pb.y - 0.5f * pb.w;
        px2[i] = pb.x + 0.5f * pb.z;  py2[i] = pb.y + 0.5f * pb.w;
        parea[i] = pb.z * pb.w;
        op[i] = out + (size_t)n * T;
    }
    __syncthreads();

    auto body = [&](int t) {
        float4 tb = tgt_boxes[t];                        // unit-stride float4
        int id = tgt_ids[t];                             // unit-stride dword
        float4 cls4 = fclsT[id];                         // ONE ds_read_b128
        float tx1 = tb.x - 0.5f * tb.z, ty1 = tb.y - 0.5f * tb.w;
        float tx2 = tb.x + 0.5f * tb.z, ty2 = tb.y + 0.5f * tb.w;
        float tarea = tb.z * tb.w;
        const float clsv[NB] = {cls4.x, cls4.y, cls4.z, cls4.w};
#pragma unroll
        for (int i = 0; i < NB; ++i) {
            float l1 = (fabsf(pcx[i] - tb.x) + fabsf(pcy[i] - tb.y))
                     + (fabsf(pw_[i] - tb.z) + fabsf(ph_[i] - tb.w));

            float ix1 = fmaxf(px1[i], tx1), iy1 = fmaxf(py1[i], ty1);
            float ix2 = fminf(px2[i], tx2), iy2 = fminf(py2[i], ty2);
            float iw = fmaxf(ix2 - ix1, 0.0f), ih = fmaxf(iy2 - iy1, 0.0f);
            float inter = iw * ih;
            float uni = parea[i] + tarea - inter;

            float ex1 = fminf(px1[i], tx1), ey1 = fminf(py1[i], ty1);
            float ex2 = fmaxf(px2[i], tx2), ey2 = fmaxf(py2[i], ty2);
            float earea = (ex2 - ex1) * (ey2 - ey1);     // wh >= 0 for [0,1) boxes

            float v = fmaf(5.0f, l1, clsv[i]);           // 5*l1 + 2*cls + 2
            v = fmaf(-2.0f, inter * __builtin_amdgcn_rcpf(uni), v);
            v = fmaf(-2.0f, uni * __builtin_amdgcn_rcpf(earea), v);
            op[i][t] = v;                                // coalesced dword store
        }
    };

    // ---- phase 2: unrolled-by-2 target sweep ----
    int t = tid;
    for (; t + 256 < T; t += 512) { body(t); body(t + 256); }
    for (; t < T; t += 256) body(t);
}

extern "C" void kernel_launch(void* const* d_in, const int* in_sizes, int n_in,
                              void* d_out, int out_size, void* d_ws, size_t ws_size,
                              hipStream_t stream) {
    const float* logits = (const float*)d_in[0];   // [bs, Q, C]
    const float* pboxes = (const float*)d_in[1];   // [bs, Q, 4]
    const float* tboxes = (const float*)d_in[2];   // [T, 4]
    const int*   tids   = (const int*)d_in[3];     // [T]

    int N = in_sizes[1] / 4;          // bs*Q = 14400
    int C = in_sizes[0] / N;          // 91
    int T = in_sizes[2] / 4;          // 1600

    int grid = (N + NB - 1) / NB;     // 3600
    fused_cost_kernel<<<grid, 256, 0, stream>>>(
        logits, (const float4*)pboxes, (const float4*)tboxes, tids,
        (float*)d_out, N, C, T);
}